// Round 7
// baseline (261.737 us; speedup 1.0000x reference)
//
#include <hip/hip_runtime.h>

// Involution: B=16, C=256, H=W=56, mid=64, GROUPS=16, GROUP_SIZE=16, K=3 (KK=9)
// All fp32. Output (16,256,56,56).
// Fully fused: conv1 (+BN+ReLU) -> LDS, conv2 -> regs, involution -> out.
//
// NOTES (measured):
//  - launch_bounds 2nd arg acts like blocks/CU here: (512,6)->40 VGPR spill-fest
//    (WRITE 260MB), (512,4)->52 VGPR minor spill (WRITE 64MB). Use (512,2) for
//    a true ~128 VGPR budget.
//  - XCD-contiguous swizzle works: FETCH == x size (52.7MB), phase-C taps all
//    hit L2/L3. Keep it.
//  - lt pitch 68 with b128 reads measured 0 bank conflicts. Keep.

#define Cn    256
#define MID   64
#define Hn    56
#define Wn    56
#define HW    3136
#define Bn    16
#define NPIX  (Bn * HW)       // 50176
#define CHW   (Cn * HW)
#define NKK   9
#define NG    16
#define GSZ   16
#define PXT   64              // pixels per block
#define BK    64              // channels per staging round (4 rounds)
#define LTP   68              // lt row pitch
#define NBLK  (NPIX / PXT)    // 784
#define BPX   (NBLK / 8)      // 98 contiguous blocks per XCD slice
#define BN_EPS 1e-5f

// ---------------------------------------------------------------------------
// prep: w1f[c*64+o] = w1[o*256+c] * scale[o];  bias1[o] = beta[o]-mean[o]*scale[o]
// ---------------------------------------------------------------------------
__global__ __launch_bounds__(256) void prep_kernel(
    const float* __restrict__ w1,
    const float* __restrict__ gamma,
    const float* __restrict__ beta,
    const float* __restrict__ mean,
    const float* __restrict__ var,
    float* __restrict__ w1f,
    float* __restrict__ bias1) {
  int idx = blockIdx.x * 256 + threadIdx.x;
  if (idx < MID * Cn) {
    int c = idx >> 6;
    int o = idx & 63;
    float scale = gamma[o] / sqrtf(var[o] + BN_EPS);
    w1f[idx] = w1[o * Cn + c] * scale;
  } else if (idx < MID * Cn + MID) {
    int o = idx - MID * Cn;
    float scale = gamma[o] / sqrtf(var[o] + BN_EPS);
    bias1[o] = beta[o] - mean[o] * scale;
  }
}

// ---------------------------------------------------------------------------
// fused: block = 64 px, 512 threads (8 waves).
// Phase A: conv1, BK=64 double-buffered (4 barrier rounds), float4 staging.
// Phase B+C per group: conv2 weights (9) in regs -> involution immediately.
// ---------------------------------------------------------------------------
__global__ __launch_bounds__(512, 2) void fused_kernel(
    const float* __restrict__ x,
    const float* __restrict__ w1f,
    const float* __restrict__ bias1,
    const float* __restrict__ w2,
    const float* __restrict__ b2,
    float* __restrict__ out) {
  __shared__ float lx[2][BK][PXT];     // 32 KB
  __shared__ float lt[PXT][LTP];       // 17.4 KB

  int tid = threadIdx.x;
  int px  = tid & 63;
  int wvu = __builtin_amdgcn_readfirstlane(tid >> 6);   // 0..7, wave-uniform

  int bid  = blockIdx.x;
  int bid2 = (bid & 7) * BPX + (bid >> 3);   // XCD slice: contiguous px range
  int px0  = bid2 * PXT;
  int b    = px0 / HW;
  int hw0  = px0 - b * HW;

  const float* xs = x + (size_t)b * CHW + hw0;   // + c*HW + px

  // staging assignment: 1024 float4 per round, 2 per thread
  int cl0 = tid >> 4;                 // 0..31
  int p40 = (tid & 15) << 2;          // 0,4,..,60
  int cl1 = cl0 + 32;                 // 32..63

  // ---------------- phase A: conv1 -> lt ----------------
  {
    float4 f0 = *(const float4*)(xs + (size_t)cl0 * HW + p40);
    float4 f1 = *(const float4*)(xs + (size_t)cl1 * HW + p40);
    *(float4*)&lx[0][cl0][p40] = f0;
    *(float4*)&lx[0][cl1][p40] = f1;
  }
  __syncthreads();

  float acc[8];
#pragma unroll
  for (int j = 0; j < 8; ++j) acc[j] = 0.0f;

  for (int k = 0; k < 4; ++k) {        // 4 c-tiles of 64
    int cur = k & 1;
    float4 f0, f1;
    if (k < 3) {
      const float* xn = xs + (size_t)(k + 1) * BK * HW;
      f0 = *(const float4*)(xn + (size_t)cl0 * HW + p40);
      f1 = *(const float4*)(xn + (size_t)cl1 * HW + p40);
    }
#pragma unroll 8
    for (int c = 0; c < BK; ++c) {
      float xv = lx[cur][c][px];
      const float* wr = w1f + ((k * BK + c) << 6) + (wvu << 3);  // uniform
#pragma unroll
      for (int q = 0; q < 2; ++q) {
        float4 w4 = *(const float4*)(wr + q * 4);
        acc[q * 4 + 0] = fmaf(xv, w4.x, acc[q * 4 + 0]);
        acc[q * 4 + 1] = fmaf(xv, w4.y, acc[q * 4 + 1]);
        acc[q * 4 + 2] = fmaf(xv, w4.z, acc[q * 4 + 2]);
        acc[q * 4 + 3] = fmaf(xv, w4.w, acc[q * 4 + 3]);
      }
    }
    if (k < 3) {
      *(float4*)&lx[1 - cur][cl0][p40] = f0;
      *(float4*)&lx[1 - cur][cl1][p40] = f1;
    }
    __syncthreads();
  }

#pragma unroll
  for (int j = 0; j < 8; ++j)
    lt[px][wvu * 8 + j] = fmaxf(acc[j] + bias1[wvu * 8 + j], 0.0f);
  __syncthreads();

  // ---------------- tap offsets (shared by both groups) ----------------
  int hw = hw0 + px;
  int h  = hw / Wn;
  int w  = hw - h * Wn;

  int boff[NKK];
  unsigned vmask = 0;
#pragma unroll
  for (int kk = 0; kk < NKK; ++kk) {
    int di = kk / 3 - 1;
    int dj = kk % 3 - 1;
    int h2 = h + di;
    int w2v = w + dj;
    bool valid = ((unsigned)h2 < (unsigned)Hn) && ((unsigned)w2v < (unsigned)Wn);
    boff[kk] = (valid ? (h2 * Wn + w2v) : hw) * 4;   // byte offset, in-bounds
    vmask |= (valid ? 1u : 0u) << kk;
  }

  const char* xpb = (const char*)(x + (size_t)b * CHW);
  float* ob = out + (size_t)b * CHW + hw;

  // ---------------- phases B+C, one group at a time ----------------
#pragma unroll
  for (int gi = 0; gi < 2; ++gi) {
    int g = wvu * 2 + gi;

    // phase B: 9 per-pixel kernel weights for this group, in registers
    float a[NKK];
#pragma unroll
    for (int kk = 0; kk < NKK; ++kk) a[kk] = b2[g * NKK + kk];

#pragma unroll
    for (int qt = 0; qt < 4; ++qt) {
      float tr[16];
#pragma unroll
      for (int q = 0; q < 4; ++q)
        *(float4*)&tr[q * 4] = *(const float4*)&lt[px][qt * 16 + q * 4];

#pragma unroll
      for (int kk = 0; kk < NKK; ++kk) {
        const float4* wr = (const float4*)(w2 + (g * NKK + kk) * MID + qt * 16);
        float s = a[kk];
#pragma unroll
        for (int q = 0; q < 4; ++q) {
          float4 w4 = wr[q];
          s = fmaf(tr[q * 4 + 0], w4.x, s);
          s = fmaf(tr[q * 4 + 1], w4.y, s);
          s = fmaf(tr[q * 4 + 2], w4.z, s);
          s = fmaf(tr[q * 4 + 3], w4.w, s);
        }
        a[kk] = s;
      }
    }

    // zero invalid taps immediately
#pragma unroll
    for (int kk = 0; kk < NKK; ++kk)
      a[kk] = ((vmask >> kk) & 1u) ? a[kk] : 0.0f;

    // phase C: involution for this group's 16 channels
#pragma unroll
    for (int c2 = 0; c2 < 8; ++c2) {
      float xv[2][NKK];
#pragma unroll
      for (int cc = 0; cc < 2; ++cc) {
        const char* xc = xpb + (size_t)(g * GSZ + c2 * 2 + cc) * HW * 4;
#pragma unroll
        for (int kk = 0; kk < NKK; ++kk)
          xv[cc][kk] = *(const float*)(xc + boff[kk]);
      }
#pragma unroll
      for (int cc = 0; cc < 2; ++cc) {
        float s = 0.0f;
#pragma unroll
        for (int kk = 0; kk < NKK; ++kk)
          s = fmaf(a[kk], xv[cc][kk], s);
        ob[(size_t)(g * GSZ + c2 * 2 + cc) * HW] = s;
      }
    }
  }
}

// ---------------------------------------------------------------------------
extern "C" void kernel_launch(void* const* d_in, const int* in_sizes, int n_in,
                              void* d_out, int out_size, void* d_ws, size_t ws_size,
                              hipStream_t stream) {
  const float* x     = (const float*)d_in[0];
  const float* w1    = (const float*)d_in[1];
  const float* gamma = (const float*)d_in[2];
  const float* beta  = (const float*)d_in[3];
  const float* mean  = (const float*)d_in[4];
  const float* var   = (const float*)d_in[5];
  const float* w2    = (const float*)d_in[6];
  const float* b2    = (const float*)d_in[7];
  float* out = (float*)d_out;

  // workspace: w1f (64 KB) | bias1 (256 B)
  char* ws = (char*)d_ws;
  float* w1f   = (float*)ws;
  float* bias1 = (float*)(ws + (size_t)MID * Cn * 4);

  prep_kernel<<<(MID * Cn + MID + 255) / 256, 256, 0, stream>>>(
      w1, gamma, beta, mean, var, w1f, bias1);
  fused_kernel<<<NBLK, 512, 0, stream>>>(x, w1f, bias1, w2, b2, out);
}

// Round 8
// 209.774 us; speedup vs baseline: 1.2477x; 1.2477x over previous
//
#include <hip/hip_runtime.h>

// Involution: B=16, C=256, H=W=56, mid=64, GROUPS=16, GROUP_SIZE=16, K=3 (KK=9)
// All fp32. Output (16,256,56,56).
// Fully fused, barrier-light: conv1 reads x straight from global (L3-resident,
// read 4x = free), ONE __syncthreads at the lt exchange, conv2 weights in regs,
// involution from global (L2/L3 hits).
//
// NOTES (measured, R1-R7):
//  - launch_bounds 2nd arg ~ blocks/CU at 512 thr: 6->40 VGPR spill-fest
//    (WRITE 260MB), 4->52+spill, 2->76 clean. For 256 thr, arg 4 => ~128 budget.
//  - XCD-contiguous swizzle: FETCH == x size once (31-53MB), taps hit L2/L3.
//  - lt pitch 68 + b128 reads / scalar writes: 0 bank conflicts measured (R6).
//  - float4 LDS staging with 256B pitch = 4-way write conflicts (R7, 3.2M) - gone.
//  - All-phase-A-staging variants stall at VALUBusy<=42%: barrier lockstep at
//    3 blocks/CU. This version: no staging, 6.1 blocks/CU.

#define Cn    256
#define MID   64
#define Hn    56
#define Wn    56
#define HW    3136
#define Bn    16
#define NPIX  (Bn * HW)       // 50176
#define CHW   (Cn * HW)
#define NKK   9
#define NG    16
#define GSZ   16
#define PXT   64              // pixels per block
#define LTP   68              // lt row pitch
#define NBLK  (NPIX / PXT)    // 1568 blocks? no: NPIX/PXT = 784 strips; 256thr
#define BPX   (NBLK / 8)      // contiguous strips per XCD slice
#define BN_EPS 1e-5f

// ---------------------------------------------------------------------------
// prep: w1f[c*64+o] = w1[o*256+c] * scale[o];  bias1[o] = beta[o]-mean[o]*scale[o]
// ---------------------------------------------------------------------------
__global__ __launch_bounds__(256) void prep_kernel(
    const float* __restrict__ w1,
    const float* __restrict__ gamma,
    const float* __restrict__ beta,
    const float* __restrict__ mean,
    const float* __restrict__ var,
    float* __restrict__ w1f,
    float* __restrict__ bias1) {
  int idx = blockIdx.x * 256 + threadIdx.x;
  if (idx < MID * Cn) {
    int c = idx >> 6;
    int o = idx & 63;
    float scale = gamma[o] / sqrtf(var[o] + BN_EPS);
    w1f[idx] = w1[o * Cn + c] * scale;
  } else if (idx < MID * Cn + MID) {
    int o = idx - MID * Cn;
    float scale = gamma[o] / sqrtf(var[o] + BN_EPS);
    bias1[o] = beta[o] - mean[o] * scale;
  }
}

// ---------------------------------------------------------------------------
// fused: block = 64 px, 256 threads (4 waves). Wave w: conv1 outputs
// w*16..w*16+15, then groups w*4..w*4+3.
// ---------------------------------------------------------------------------
__global__ __launch_bounds__(256, 4) void fused_kernel(
    const float* __restrict__ x,
    const float* __restrict__ w1f,
    const float* __restrict__ bias1,
    const float* __restrict__ w2,
    const float* __restrict__ b2,
    float* __restrict__ out) {
  __shared__ float lt[PXT][LTP];       // 17.4 KB, only LDS in kernel

  int tid = threadIdx.x;
  int px  = tid & 63;
  int wvu = __builtin_amdgcn_readfirstlane(tid >> 6);   // 0..3, wave-uniform

  int bid  = blockIdx.x;
  int bid2 = (bid & 7) * BPX + (bid >> 3);   // XCD slice: contiguous px range
  int px0  = bid2 * PXT;
  int b    = px0 / HW;
  int hw0  = px0 - b * HW;

  const float* xp = x + (size_t)b * CHW + hw0 + px;    // + c*HW

  // ---------------- phase A: conv1, no LDS, reg double-buffer ----------------
  float acc[16];
#pragma unroll
  for (int j = 0; j < 16; ++j) acc[j] = 0.0f;

  float xc[8], xn[8];
#pragma unroll
  for (int i = 0; i < 8; ++i) xc[i] = xp[(size_t)i * HW];

  for (int k = 0; k < 32; k += 2) {    // 8 channels per half-step
    // load odd batch while computing even
#pragma unroll
    for (int i = 0; i < 8; ++i) xn[i] = xp[(size_t)((k + 1) * 8 + i) * HW];

    {
      const float* wb = w1f + (k * 8) * MID + (wvu << 4);   // uniform
#pragma unroll
      for (int i = 0; i < 8; ++i) {
        float xv = xc[i];
        const float* wr = wb + i * MID;
#pragma unroll
        for (int q = 0; q < 4; ++q) {
          float4 w4 = *(const float4*)(wr + q * 4);
          acc[q * 4 + 0] = fmaf(xv, w4.x, acc[q * 4 + 0]);
          acc[q * 4 + 1] = fmaf(xv, w4.y, acc[q * 4 + 1]);
          acc[q * 4 + 2] = fmaf(xv, w4.z, acc[q * 4 + 2]);
          acc[q * 4 + 3] = fmaf(xv, w4.w, acc[q * 4 + 3]);
        }
      }
    }

    // load next even batch while computing odd
    if (k < 30) {
#pragma unroll
      for (int i = 0; i < 8; ++i) xc[i] = xp[(size_t)((k + 2) * 8 + i) * HW];
    }

    {
      const float* wb = w1f + ((k + 1) * 8) * MID + (wvu << 4);
#pragma unroll
      for (int i = 0; i < 8; ++i) {
        float xv = xn[i];
        const float* wr = wb + i * MID;
#pragma unroll
        for (int q = 0; q < 4; ++q) {
          float4 w4 = *(const float4*)(wr + q * 4);
          acc[q * 4 + 0] = fmaf(xv, w4.x, acc[q * 4 + 0]);
          acc[q * 4 + 1] = fmaf(xv, w4.y, acc[q * 4 + 1]);
          acc[q * 4 + 2] = fmaf(xv, w4.z, acc[q * 4 + 2]);
          acc[q * 4 + 3] = fmaf(xv, w4.w, acc[q * 4 + 3]);
        }
      }
    }
  }

#pragma unroll
  for (int j = 0; j < 16; ++j) {
    int o = wvu * 16 + j;
    lt[px][o] = fmaxf(acc[j] + bias1[o], 0.0f);
  }
  __syncthreads();

  // ---------------- tap offsets ----------------
  int hw = hw0 + px;
  int h  = hw / Wn;
  int w  = hw - h * Wn;

  int boff[NKK];
  unsigned vmask = 0;
#pragma unroll
  for (int kk = 0; kk < NKK; ++kk) {
    int di = kk / 3 - 1;
    int dj = kk % 3 - 1;
    int h2 = h + di;
    int w2v = w + dj;
    bool valid = ((unsigned)h2 < (unsigned)Hn) && ((unsigned)w2v < (unsigned)Wn);
    boff[kk] = (valid ? (h2 * Wn + w2v) : hw) * 4;   // byte offset, in-bounds
    vmask |= (valid ? 1u : 0u) << kk;
  }

  const char* xpb = (const char*)(x + (size_t)b * CHW);
  float* ob = out + (size_t)b * CHW + hw;

  // ---------------- phases B+C, one group at a time ----------------
#pragma unroll
  for (int gi = 0; gi < 4; ++gi) {
    int g = wvu * 4 + gi;

    // phase B: 9 per-pixel kernel weights for this group, in registers
    float a[NKK];
#pragma unroll
    for (int kk = 0; kk < NKK; ++kk) a[kk] = b2[g * NKK + kk];

#pragma unroll
    for (int qt = 0; qt < 4; ++qt) {
      float tr[16];
#pragma unroll
      for (int q = 0; q < 4; ++q)
        *(float4*)&tr[q * 4] = *(const float4*)&lt[px][qt * 16 + q * 4];

#pragma unroll
      for (int kk = 0; kk < NKK; ++kk) {
        const float4* wr = (const float4*)(w2 + (g * NKK + kk) * MID + qt * 16);
        float s = a[kk];
#pragma unroll
        for (int q = 0; q < 4; ++q) {
          float4 w4 = wr[q];
          s = fmaf(tr[q * 4 + 0], w4.x, s);
          s = fmaf(tr[q * 4 + 1], w4.y, s);
          s = fmaf(tr[q * 4 + 2], w4.z, s);
          s = fmaf(tr[q * 4 + 3], w4.w, s);
        }
        a[kk] = s;
      }
    }

    // zero invalid taps
#pragma unroll
    for (int kk = 0; kk < NKK; ++kk)
      a[kk] = ((vmask >> kk) & 1u) ? a[kk] : 0.0f;

    // phase C: involution for this group's 16 channels
#pragma unroll
    for (int c2 = 0; c2 < 8; ++c2) {
      float xv[2][NKK];
#pragma unroll
      for (int cc = 0; cc < 2; ++cc) {
        const char* xcb = xpb + (size_t)(g * GSZ + c2 * 2 + cc) * HW * 4;
#pragma unroll
        for (int kk = 0; kk < NKK; ++kk)
          xv[cc][kk] = *(const float*)(xcb + boff[kk]);
      }
#pragma unroll
      for (int cc = 0; cc < 2; ++cc) {
        float s = 0.0f;
#pragma unroll
        for (int kk = 0; kk < NKK; ++kk)
          s = fmaf(a[kk], xv[cc][kk], s);
        ob[(size_t)(g * GSZ + c2 * 2 + cc) * HW] = s;
      }
    }
  }
}

// ---------------------------------------------------------------------------
extern "C" void kernel_launch(void* const* d_in, const int* in_sizes, int n_in,
                              void* d_out, int out_size, void* d_ws, size_t ws_size,
                              hipStream_t stream) {
  const float* x     = (const float*)d_in[0];
  const float* w1    = (const float*)d_in[1];
  const float* gamma = (const float*)d_in[2];
  const float* beta  = (const float*)d_in[3];
  const float* mean  = (const float*)d_in[4];
  const float* var   = (const float*)d_in[5];
  const float* w2    = (const float*)d_in[6];
  const float* b2    = (const float*)d_in[7];
  float* out = (float*)d_out;

  // workspace: w1f (64 KB) | bias1 (256 B)
  char* ws = (char*)d_ws;
  float* w1f   = (float*)ws;
  float* bias1 = (float*)(ws + (size_t)MID * Cn * 4);

  prep_kernel<<<(MID * Cn + MID + 255) / 256, 256, 0, stream>>>(
      w1, gamma, beta, mean, var, w1f, bias1);
  fused_kernel<<<NBLK, 256, 0, stream>>>(x, w1f, bias1, w2, b2, out);
}